// Round 8
// baseline (454.438 us; speedup 1.0000x reference)
//
#include <hip/hip_runtime.h>
#include <hip/hip_bf16.h>
#include <cstddef>

// ToxicityGAT: 2-layer GAT (4 heads -> 1 head) + linear classifier.
// N=50000, E=800000 (+N self loops), IN=128, HID=64, HEADS=4.
// R8: fp8 payload REVERTED (R7: absmax 2.44e-3 > 2.23e-3 threshold; e4m3
// quantization of the payload is fundamentally ~2.4e-3). Keep bf16 payload
// (4.9e-4) + R7's untested structure: 2 waves/node + LDS combine in both
// agg kernels (A/B on latency vs random-gather-BW bound at fixed dtype).

#define HEADS 4
#define HID 64
#define IN_DIM 128

using bf16x8 = __attribute__((ext_vector_type(8))) short;
using f32x4  = __attribute__((ext_vector_type(4))) float;

__device__ __forceinline__ float us2f(unsigned short u) {
    return __uint_as_float((unsigned int)u << 16);
}
__device__ __forceinline__ unsigned short f2us(float f) {
    __hip_bfloat16 b = __float2bfloat16(f);
    return __builtin_bit_cast(unsigned short, b);
}

// ---------------- setup: deg init + W1/W2 transpose+bf16 (one launch) ------
__global__ __launch_bounds__(256) void setup_kernel(const float* __restrict__ W1,
                                                    const float* __restrict__ W2,
                                                    unsigned short* __restrict__ W1T,
                                                    unsigned short* __restrict__ W2T,
                                                    int* __restrict__ deg, int N) {
    int i = blockIdx.x * 256 + threadIdx.x;
    if (i < N) deg[i] = 1;                       // self loop
    if (i < IN_DIM * 256) {                      // W1 [128][256] -> W1T [256][128]
        int k = i >> 8, n = i & 255;
        W1T[n * IN_DIM + k] = f2us(W1[i]);
    }
    if (i < 256 * 64) {                          // W2 [256][64] -> W2T [64][256]
        int k = i >> 6, n = i & 63;
        W2T[n * 256 + k] = f2us(W2[i]);
    }
}

// ---------------- MFMA GEMM: C = A @ BT^T ----------------------------------
// AF32: A fp32, converted to bf16 during LDS staging.
// INTERLEAVE: write head-interleaved g1b[n][d][h] (d=0..63, h=0..3).
template <int BN, int BK, int KFULL, bool INTERLEAVE, bool AF32>
__global__ __launch_bounds__(256) void gemm_mfma_kernel(
    const void* __restrict__ Av,
    const unsigned short* __restrict__ BT,
    unsigned short* __restrict__ C,
    int M, int Nfull) {
    constexpr int LDK = BK + 8;
    constexpr int NT = BN / 16;
    constexpr int KC = BK / 8;
    __shared__ unsigned short As[64 * LDK];
    __shared__ unsigned short Bs[BN * LDK];
    const int tid = threadIdx.x;
    const int wave = tid >> 6, lane = tid & 63;
    const int row0 = blockIdx.y * 64;
    const int col0 = blockIdx.x * BN;
    f32x4 acc[NT] = {};
    for (int k0 = 0; k0 < KFULL; k0 += BK) {
        for (int c = tid; c < 64 * KC; c += 256) {
            int r = c / KC, kc = c - r * KC;
            int row = row0 + r; if (row >= M) row = M - 1;  // clamp: stay in-bounds
            if constexpr (AF32) {
                const float* src = (const float*)Av + (size_t)row * KFULL + k0 + kc * 8;
                float4 v0 = *(const float4*)(src);
                float4 v1 = *(const float4*)(src + 4);
                *(ushort4*)(As + r * LDK + kc * 8) =
                    make_ushort4(f2us(v0.x), f2us(v0.y), f2us(v0.z), f2us(v0.w));
                *(ushort4*)(As + r * LDK + kc * 8 + 4) =
                    make_ushort4(f2us(v1.x), f2us(v1.y), f2us(v1.z), f2us(v1.w));
            } else {
                *(bf16x8*)(As + r * LDK + kc * 8) =
                    *(const bf16x8*)((const unsigned short*)Av + (size_t)row * KFULL + k0 + kc * 8);
            }
        }
        for (int c = tid; c < BN * KC; c += 256) {
            int r = c / KC, kc = c - r * KC;
            *(bf16x8*)(Bs + r * LDK + kc * 8) =
                *(const bf16x8*)(BT + (size_t)(col0 + r) * KFULL + k0 + kc * 8);
        }
        __syncthreads();
        const int arow = wave * 16 + (lane & 15);
        const int kb = (lane >> 4) * 8;
#pragma unroll
        for (int ks = 0; ks < BK; ks += 32) {
            bf16x8 af = *(const bf16x8*)(As + arow * LDK + ks + kb);
#pragma unroll
            for (int nt = 0; nt < NT; ++nt) {
                bf16x8 bfv = *(const bf16x8*)(Bs + (nt * 16 + (lane & 15)) * LDK + ks + kb);
                acc[nt] = __builtin_amdgcn_mfma_f32_16x16x32_bf16(af, bfv, acc[nt], 0, 0, 0);
            }
        }
        __syncthreads();
    }
    // C/D: col = lane&15, row = (lane>>4)*4 + reg
    const int crow0 = row0 + wave * 16 + ((lane >> 4) << 2);
#pragma unroll
    for (int nt = 0; nt < NT; ++nt) {
        const int col = col0 + nt * 16 + (lane & 15);
#pragma unroll
        for (int j = 0; j < 4; ++j) {
            const int row = crow0 + j;
            if (row < M) {
                size_t off = INTERLEAVE
                    ? (size_t)row * 256 + (size_t)(col & 63) * 4 + (col >> 6)
                    : (size_t)row * Nfull + col;
                C[off] = f2us(acc[nt][j]);
            }
        }
    }
}

// ---------------- CSR build ----------------
__global__ void deg_count_kernel(const int* __restrict__ dst, int* __restrict__ deg, int E) {
    int e = blockIdx.x * 256 + threadIdx.x;
    if (e < E) atomicAdd(&deg[dst[e]], 1);
}
__global__ __launch_bounds__(256) void scan1_kernel(const int* __restrict__ deg,
                                                    int* __restrict__ bsum, int N) {
    const int i = blockIdx.x * 256 + threadIdx.x;
    const int lane = threadIdx.x & 63, w = threadIdx.x >> 6;
    int v = (i < N) ? deg[i] : 0;
#pragma unroll
    for (int off = 32; off; off >>= 1) v += __shfl_xor(v, off, 64);
    __shared__ int ws[4];
    if (lane == 0) ws[w] = v;
    __syncthreads();
    if (threadIdx.x == 0) bsum[blockIdx.x] = ws[0] + ws[1] + ws[2] + ws[3];
}
__global__ __launch_bounds__(256) void scan2_kernel(const int* __restrict__ bsum,
                                                    int* __restrict__ boff, int nb) {
    const int tid = threadIdx.x, lane = tid & 63, w = tid >> 6;
    int v = (tid < nb) ? bsum[tid] : 0;
    int x = v;
#pragma unroll
    for (int off = 1; off < 64; off <<= 1) {
        int y = __shfl_up(x, off, 64);
        if (lane >= off) x += y;
    }
    __shared__ int ws[4];
    if (lane == 63) ws[w] = x;
    __syncthreads();
    int add = 0;
    for (int i = 0; i < w; ++i) add += ws[i];
    x += add;
    if (tid < nb) boff[tid] = x - v;      // exclusive
    if (tid == 255) boff[nb] = x;         // total
}
__global__ __launch_bounds__(256) void scan3_kernel(const int* __restrict__ deg,
                                                    const int* __restrict__ boff,
                                                    int* __restrict__ row_ptr, int N) {
    const int i = blockIdx.x * 256 + threadIdx.x;
    const int tid = threadIdx.x, lane = tid & 63, w = tid >> 6;
    int v = (i < N) ? deg[i] : 0;
    int x = v;
#pragma unroll
    for (int off = 1; off < 64; off <<= 1) {
        int y = __shfl_up(x, off, 64);
        if (lane >= off) x += y;
    }
    __shared__ int ws[4];
    if (lane == 63) ws[w] = x;
    __syncthreads();
    int add = 0;
    for (int k = 0; k < w; ++k) add += ws[k];
    x += add;
    int excl = x - v + boff[blockIdx.x];
    if (i < N) row_ptr[i] = excl;
    if (i == N - 1) row_ptr[N] = excl + v;
}
__global__ void selfloop_kernel(const int* __restrict__ row_ptr, int* __restrict__ colA,
                                int* __restrict__ dstA, int* __restrict__ fill, int N) {
    int n = blockIdx.x * 256 + threadIdx.x;
    if (n < N) {
        int p = row_ptr[n];
        colA[p] = n;
        dstA[p] = n;
        fill[n] = p + 1;
    }
}
__global__ void scatter_kernel(const int* __restrict__ src, const int* __restrict__ dst,
                               int* __restrict__ fill, int* __restrict__ colA,
                               int* __restrict__ dstA, int E) {
    int e = blockIdx.x * 256 + threadIdx.x;
    if (e < E) {
        int d = dst[e];
        int pos = atomicAdd(&fill[d], 1);
        colA[pos] = src[e];
        dstA[pos] = d;
    }
}

// ---------------- attention score dots (one wave per node) ----------------
__global__ __launch_bounds__(256) void alpha1_kernel(const unsigned short* __restrict__ g1,
                                                     const float* __restrict__ a_src,
                                                     const float* __restrict__ a_dst,
                                                     float* __restrict__ as1,
                                                     float* __restrict__ ad1, int N) {
    int wid = (blockIdx.x * 256 + threadIdx.x) >> 6;
    int lane = threadIdx.x & 63;
    if (wid >= N) return;
    ushort4 g = *(const ushort4*)(g1 + (size_t)wid * 256 + lane * 4);  // heads 0..3 at d=lane
    float f0 = us2f(g.x), f1 = us2f(g.y), f2 = us2f(g.z), f3 = us2f(g.w);
    float s0 = f0 * a_src[lane],       d0 = f0 * a_dst[lane];
    float s1 = f1 * a_src[64 + lane],  d1 = f1 * a_dst[64 + lane];
    float s2 = f2 * a_src[128 + lane], d2 = f2 * a_dst[128 + lane];
    float s3 = f3 * a_src[192 + lane], d3 = f3 * a_dst[192 + lane];
#pragma unroll
    for (int off = 32; off; off >>= 1) {
        s0 += __shfl_xor(s0, off, 64); d0 += __shfl_xor(d0, off, 64);
        s1 += __shfl_xor(s1, off, 64); d1 += __shfl_xor(d1, off, 64);
        s2 += __shfl_xor(s2, off, 64); d2 += __shfl_xor(d2, off, 64);
        s3 += __shfl_xor(s3, off, 64); d3 += __shfl_xor(d3, off, 64);
    }
    if (lane == 0) {
        *(float4*)(as1 + (size_t)wid * 4) = make_float4(s0, s1, s2, s3);
        *(float4*)(ad1 + (size_t)wid * 4) = make_float4(d0, d1, d2, d3);
    }
}
__global__ __launch_bounds__(256) void alpha2_kernel(const unsigned short* __restrict__ g2,
                                                     const float* __restrict__ a_src,
                                                     const float* __restrict__ a_dst,
                                                     float* __restrict__ as2,
                                                     float* __restrict__ ad2, int N) {
    int wid = (blockIdx.x * 256 + threadIdx.x) >> 6;
    int lane = threadIdx.x & 63;
    if (wid >= N) return;
    float v = us2f(g2[(size_t)wid * 64 + lane]);
    float s = v * a_src[lane];
    float d = v * a_dst[lane];
#pragma unroll
    for (int off = 32; off; off >>= 1) {
        s += __shfl_xor(s, off, 64);
        d += __shfl_xor(d, off, 64);
    }
    if (lane == 0) { as2[wid] = s; ad2[wid] = d; }
}

// ---------------- edge-parallel softmax-weight precompute ----------------
template <int H>
__global__ __launch_bounds__(256) void wkernel(const int* __restrict__ colA,
                                               const int* __restrict__ dstA,
                                               const float* __restrict__ as,
                                               const float* __restrict__ ad,
                                               float* __restrict__ wA, int NNZ) {
    int p = blockIdx.x * 256 + threadIdx.x;
    if (p >= NNZ) return;
    const int src = colA[p], dst = dstA[p];
    if constexpr (H == 4) {
        float4 s = *(const float4*)(as + (size_t)src * 4);
        float4 d = *(const float4*)(ad + (size_t)dst * 4);
        float e;
        float4 w;
        e = s.x + d.x; e = e > 0.f ? e : 0.2f * e; w.x = __expf(e);
        e = s.y + d.y; e = e > 0.f ? e : 0.2f * e; w.y = __expf(e);
        e = s.z + d.z; e = e > 0.f ? e : 0.2f * e; w.z = __expf(e);
        e = s.w + d.w; e = e > 0.f ? e : 0.2f * e; w.w = __expf(e);
        *(float4*)(wA + (size_t)p * 4) = w;
    } else {
        float e = as[src] + ad[dst];
        e = e > 0.f ? e : 0.2f * e;
        wA[p] = __expf(e);
    }
}

// ---------------- layer-1 aggregation: 2 waves/node, 8-deep, bf16 payload --
__global__ __launch_bounds__(256) void agg1_kernel(
    const unsigned short* __restrict__ g1, const float* __restrict__ wA,
    const int* __restrict__ row_ptr, const int* __restrict__ colA,
    const float* __restrict__ b1, unsigned short* __restrict__ h1b, int N) {
    const int gw = (blockIdx.x * 256 + threadIdx.x) >> 6;  // global wave
    const int node = gw >> 1, sub = gw & 1;
    const int lane = threadIdx.x & 63, lw = threadIdx.x >> 6;
    __shared__ float sh_a[4][64][4];
    __shared__ float sh_s[4][4];
    float s0 = 0.f, s1 = 0.f, s2 = 0.f, s3 = 0.f;
    float a0 = 0.f, a1 = 0.f, a2 = 0.f, a3 = 0.f;
    if (node < N) {
        const int beg = row_ptr[node], end = row_ptr[node + 1];
        for (int idx = beg + sub * 8; idx < end; idx += 16) {
            int p[8];
#pragma unroll
            for (int j = 0; j < 8; ++j) { int q = idx + j; p[j] = q < end ? q : end - 1; }
            int si[8];
#pragma unroll
            for (int j = 0; j < 8; ++j) si[j] = colA[p[j]];
            float4 w[8];
#pragma unroll
            for (int j = 0; j < 8; ++j) w[j] = *(const float4*)(wA + (size_t)p[j] * 4);
            ushort4 g[8];
#pragma unroll
            for (int j = 0; j < 8; ++j)
                g[j] = *(const ushort4*)(g1 + ((size_t)si[j] << 8) + lane * 4);
#pragma unroll
            for (int j = 0; j < 8; ++j) {
                const float m = (idx + j < end) ? 1.f : 0.f;
                const float wx = w[j].x * m, wy = w[j].y * m;
                const float wz = w[j].z * m, ww = w[j].w * m;
                s0 += wx; a0 += wx * us2f(g[j].x);
                s1 += wy; a1 += wy * us2f(g[j].y);
                s2 += wz; a2 += wz * us2f(g[j].z);
                s3 += ww; a3 += ww * us2f(g[j].w);
            }
        }
    }
    sh_a[lw][lane][0] = a0; sh_a[lw][lane][1] = a1;
    sh_a[lw][lane][2] = a2; sh_a[lw][lane][3] = a3;
    if (lane == 0) {
        sh_s[lw][0] = s0; sh_s[lw][1] = s1; sh_s[lw][2] = s2; sh_s[lw][3] = s3;
    }
    __syncthreads();
    if (sub == 0 && node < N) {
        a0 += sh_a[lw + 1][lane][0]; a1 += sh_a[lw + 1][lane][1];
        a2 += sh_a[lw + 1][lane][2]; a3 += sh_a[lw + 1][lane][3];
        s0 += sh_s[lw + 1][0]; s1 += sh_s[lw + 1][1];
        s2 += sh_s[lw + 1][2]; s3 += sh_s[lw + 1][3];
        size_t base = (size_t)node * 256;
        float o;
        o = a0 / s0 + b1[lane];       o = o > 0.f ? o : expm1f(o); h1b[base + lane]       = f2us(o);
        o = a1 / s1 + b1[64 + lane];  o = o > 0.f ? o : expm1f(o); h1b[base + 64 + lane]  = f2us(o);
        o = a2 / s2 + b1[128 + lane]; o = o > 0.f ? o : expm1f(o); h1b[base + 128 + lane] = f2us(o);
        o = a3 / s3 + b1[192 + lane]; o = o > 0.f ? o : expm1f(o); h1b[base + 192 + lane] = f2us(o);
    }
}

// ---------------- layer-2 aggregation + classifier: 2 waves/node, 16-deep --
__global__ __launch_bounds__(256) void agg2_kernel(
    const unsigned short* __restrict__ g2, const float* __restrict__ wA,
    const int* __restrict__ row_ptr, const int* __restrict__ colA,
    const float* __restrict__ b2, const float* __restrict__ Wc,
    const float* __restrict__ bc, float* __restrict__ out, int N) {
    const int gw = (blockIdx.x * 256 + threadIdx.x) >> 6;
    const int node = gw >> 1, sub = gw & 1;
    const int lane = threadIdx.x & 63, lw = threadIdx.x >> 6;
    __shared__ float sh_a[4][64];
    __shared__ float sh_s[4];
    float s = 0.f, a = 0.f;
    if (node < N) {
        const int beg = row_ptr[node], end = row_ptr[node + 1];
        for (int idx = beg + sub * 16; idx < end; idx += 32) {
            int p[16];
#pragma unroll
            for (int j = 0; j < 16; ++j) { int q = idx + j; p[j] = q < end ? q : end - 1; }
            int si[16];
#pragma unroll
            for (int j = 0; j < 16; ++j) si[j] = colA[p[j]];
            float w[16];
#pragma unroll
            for (int j = 0; j < 16; ++j) w[j] = wA[p[j]];
            unsigned short g[16];
#pragma unroll
            for (int j = 0; j < 16; ++j) g[j] = g2[((size_t)si[j] << 6) + lane];
#pragma unroll
            for (int j = 0; j < 16; ++j) {
                const float m = (idx + j < end) ? 1.f : 0.f;
                const float wj = w[j] * m;
                s += wj; a += wj * us2f(g[j]);
            }
        }
    }
    sh_a[lw][lane] = a;
    if (lane == 0) sh_s[lw] = s;
    __syncthreads();
    if (sub == 0 && node < N) {
        a += sh_a[lw + 1][lane];
        s += sh_s[lw + 1];
        float h = a / s + b2[lane];
        h = h > 0.f ? h : expm1f(h);
        float c0 = h * Wc[lane * 2 + 0];
        float c1 = h * Wc[lane * 2 + 1];
#pragma unroll
        for (int off = 32; off; off >>= 1) {
            c0 += __shfl_xor(c0, off, 64);
            c1 += __shfl_xor(c1, off, 64);
        }
        if (lane == 0) {
            out[(size_t)node * 2 + 0] = c0 + bc[0];
            out[(size_t)node * 2 + 1] = c1 + bc[1];
        }
    }
}

extern "C" void kernel_launch(void* const* d_in, const int* in_sizes, int n_in,
                              void* d_out, int out_size, void* d_ws, size_t ws_size,
                              hipStream_t stream) {
    const float* x        = (const float*)d_in[0];
    const int*   ei       = (const int*)d_in[1];
    const float* W1       = (const float*)d_in[2];
    const float* att1_src = (const float*)d_in[3];
    const float* att1_dst = (const float*)d_in[4];
    const float* b1       = (const float*)d_in[5];
    const float* W2       = (const float*)d_in[6];
    const float* att2_src = (const float*)d_in[7];
    const float* att2_dst = (const float*)d_in[8];
    const float* b2       = (const float*)d_in[9];
    const float* Wc       = (const float*)d_in[10];
    const float* bc       = (const float*)d_in[11];
    float* out = (float*)d_out;

    const int N = in_sizes[0] / IN_DIM;
    const int E = in_sizes[1] / 2;
    const int NNZ = E + N;
    const int* srcI = ei;
    const int* dstI = ei + E;

    // workspace layout (~84 MB): bf16 bufs | fp32 | ints
    unsigned short* g1b = (unsigned short*)d_ws;      // N*256 (head-interleaved)
    unsigned short* h1b = g1b + (size_t)N * 256;      // N*256
    unsigned short* g2b = h1b + (size_t)N * 256;      // N*64
    unsigned short* W1T = g2b + (size_t)N * 64;       // 256*128
    unsigned short* W2T = W1T + 256 * 128;            // 64*256
    float* as1 = (float*)(W2T + 64 * 256);            // N*4
    float* ad1 = as1 + (size_t)N * 4;                 // N*4
    float* as2 = ad1 + (size_t)N * 4;                 // N
    float* ad2 = as2 + N;                             // N
    float* wA1 = ad2 + N;                             // NNZ*4 (16B-aligned)
    float* wA2 = wA1 + (size_t)NNZ * 4;               // NNZ
    int* deg     = (int*)(wA2 + NNZ);                 // N
    int* row_ptr = deg + N;                           // N+1
    int* fill    = row_ptr + N + 1;                   // N
    int* bsum    = fill + N;                          // 256
    int* boff    = bsum + 256;                        // 257 (+pad)
    int* colA    = boff + 260;                        // NNZ
    int* dstA    = colA + NNZ;                        // NNZ (guards colA tail overread)

    const int nB = (N + 255) / 256;
    const int eB = (E + 255) / 256;
    const int pB = (NNZ + 255) / 256;
    const int wB = ((N * 64) + 255) / 256;            // one wave per node
    const int w2B = ((N * 128) + 255) / 256;          // two waves per node
    const int nb = nB;                                // scan partials (<=256)

    // setup (deg init + weight transposes, one launch)
    setup_kernel<<<nB, 256, 0, stream>>>(W1, W2, W1T, W2T, deg, N);

    // CSR build
    deg_count_kernel<<<eB, 256, 0, stream>>>(dstI, deg, E);
    scan1_kernel<<<nB, 256, 0, stream>>>(deg, bsum, N);
    scan2_kernel<<<1, 256, 0, stream>>>(bsum, boff, nb);
    scan3_kernel<<<nB, 256, 0, stream>>>(deg, boff, row_ptr, N);
    selfloop_kernel<<<nB, 256, 0, stream>>>(row_ptr, colA, dstA, fill, N);
    scatter_kernel<<<eB, 256, 0, stream>>>(srcI, dstI, fill, colA, dstA, E);

    // layer 1: g1 = x @ W1 (fp32 A staged to bf16), bf16 head-interleaved out
    gemm_mfma_kernel<128, 128, 128, true, true>
        <<<dim3(2, (N + 63) / 64), 256, 0, stream>>>(x, W1T, g1b, N, 256);
    alpha1_kernel<<<wB, 256, 0, stream>>>(g1b, att1_src, att1_dst, as1, ad1, N);
    wkernel<4><<<pB, 256, 0, stream>>>(colA, dstA, as1, ad1, wA1, NNZ);
    agg1_kernel<<<w2B, 256, 0, stream>>>(g1b, wA1, row_ptr, colA, b1, h1b, N);

    // layer 2: g2 = h1 @ W2 (bf16)
    gemm_mfma_kernel<64, 128, 256, false, false>
        <<<dim3(1, (N + 63) / 64), 256, 0, stream>>>(h1b, W2T, g2b, N, 64);
    alpha2_kernel<<<wB, 256, 0, stream>>>(g2b, att2_src, att2_dst, as2, ad2, N);
    wkernel<1><<<pB, 256, 0, stream>>>(colA, dstA, as2, ad2, wA2, NNZ);
    agg2_kernel<<<w2B, 256, 0, stream>>>(g2b, wA2, row_ptr, colA, b2, Wc, bc, out, N);
}

// Round 9
// 363.497 us; speedup vs baseline: 1.2502x; 1.2502x over previous
//
#include <hip/hip_runtime.h>
#include <hip/hip_bf16.h>
#include <cstddef>

// ToxicityGAT: 2-layer GAT (4 heads -> 1 head) + linear classifier.
// N=50000, E=800000 (+N self loops), IN=128, HID=64, HEADS=4.
// R9: revert agg to R6 1-wave/node 8/16-deep (R8 2-wave split regressed
// 93->139us: barrier coupling + idle epilogue waves). New: paired int2
// edge array (halves CSR scatter line traffic), alpha dots fused into
// GEMM epilogues (2 fewer kernels, one less 25.6MB pass).

#define HEADS 4
#define HID 64
#define IN_DIM 128

using bf16x8 = __attribute__((ext_vector_type(8))) short;
using f32x4  = __attribute__((ext_vector_type(4))) float;

__device__ __forceinline__ float us2f(unsigned short u) {
    return __uint_as_float((unsigned int)u << 16);
}
__device__ __forceinline__ unsigned short f2us(float f) {
    __hip_bfloat16 b = __float2bfloat16(f);
    return __builtin_bit_cast(unsigned short, b);
}

// ---------------- setup: deg init + W1/W2 transpose+bf16 (one launch) ------
__global__ __launch_bounds__(256) void setup_kernel(const float* __restrict__ W1,
                                                    const float* __restrict__ W2,
                                                    unsigned short* __restrict__ W1T,
                                                    unsigned short* __restrict__ W2T,
                                                    int* __restrict__ deg, int N) {
    int i = blockIdx.x * 256 + threadIdx.x;
    if (i < N) deg[i] = 1;                       // self loop
    if (i < IN_DIM * 256) {                      // W1 [128][256] -> W1T [256][128]
        int k = i >> 8, n = i & 255;
        W1T[n * IN_DIM + k] = f2us(W1[i]);
    }
    if (i < 256 * 64) {                          // W2 [256][64] -> W2T [64][256]
        int k = i >> 6, n = i & 63;
        W2T[n * 256 + k] = f2us(W2[i]);
    }
}

// ---------------- MFMA GEMM + fused alpha dots ------------------------------
// C = A @ BT^T. AF32: A fp32->bf16 during staging. INTERLEAVE: g1b[n][d][h].
// NHEAD>0: epilogue computes per-row per-head dots with att_src/att_dst and
// writes as_out/ad_out (each wave owns full rows since BN == Nfull).
template <int BN, int BK, int KFULL, bool INTERLEAVE, bool AF32, int NHEAD>
__global__ __launch_bounds__(256) void gemm_mfma_kernel(
    const void* __restrict__ Av,
    const unsigned short* __restrict__ BT,
    unsigned short* __restrict__ C,
    const float* __restrict__ att_src, const float* __restrict__ att_dst,
    float* __restrict__ as_out, float* __restrict__ ad_out,
    int M, int Nfull) {
    constexpr int LDK = BK + 8;
    constexpr int NT = BN / 16;
    constexpr int KC = BK / 8;
    __shared__ unsigned short As[64 * LDK];
    __shared__ unsigned short Bs[BN * LDK];
    const int tid = threadIdx.x;
    const int wave = tid >> 6, lane = tid & 63;
    const int row0 = blockIdx.y * 64;
    const int col0 = blockIdx.x * BN;
    f32x4 acc[NT] = {};
    for (int k0 = 0; k0 < KFULL; k0 += BK) {
        for (int c = tid; c < 64 * KC; c += 256) {
            int r = c / KC, kc = c - r * KC;
            int row = row0 + r; if (row >= M) row = M - 1;  // clamp: stay in-bounds
            if constexpr (AF32) {
                const float* src = (const float*)Av + (size_t)row * KFULL + k0 + kc * 8;
                float4 v0 = *(const float4*)(src);
                float4 v1 = *(const float4*)(src + 4);
                *(ushort4*)(As + r * LDK + kc * 8) =
                    make_ushort4(f2us(v0.x), f2us(v0.y), f2us(v0.z), f2us(v0.w));
                *(ushort4*)(As + r * LDK + kc * 8 + 4) =
                    make_ushort4(f2us(v1.x), f2us(v1.y), f2us(v1.z), f2us(v1.w));
            } else {
                *(bf16x8*)(As + r * LDK + kc * 8) =
                    *(const bf16x8*)((const unsigned short*)Av + (size_t)row * KFULL + k0 + kc * 8);
            }
        }
        for (int c = tid; c < BN * KC; c += 256) {
            int r = c / KC, kc = c - r * KC;
            *(bf16x8*)(Bs + r * LDK + kc * 8) =
                *(const bf16x8*)(BT + (size_t)(col0 + r) * KFULL + k0 + kc * 8);
        }
        __syncthreads();
        const int arow = wave * 16 + (lane & 15);
        const int kb = (lane >> 4) * 8;
#pragma unroll
        for (int ks = 0; ks < BK; ks += 32) {
            bf16x8 af = *(const bf16x8*)(As + arow * LDK + ks + kb);
#pragma unroll
            for (int nt = 0; nt < NT; ++nt) {
                bf16x8 bfv = *(const bf16x8*)(Bs + (nt * 16 + (lane & 15)) * LDK + ks + kb);
                acc[nt] = __builtin_amdgcn_mfma_f32_16x16x32_bf16(af, bfv, acc[nt], 0, 0, 0);
            }
        }
        __syncthreads();
    }
    // C/D: col = lane&15, row = (lane>>4)*4 + reg
    const int crow0 = row0 + wave * 16 + ((lane >> 4) << 2);
#pragma unroll
    for (int nt = 0; nt < NT; ++nt) {
        const int col = col0 + nt * 16 + (lane & 15);
#pragma unroll
        for (int j = 0; j < 4; ++j) {
            const int row = crow0 + j;
            if (row < M) {
                size_t off = INTERLEAVE
                    ? (size_t)row * 256 + (size_t)(col & 63) * 4 + (col >> 6)
                    : (size_t)row * Nfull + col;
                C[off] = f2us(acc[nt][j]);
            }
        }
    }
    // fused alpha: per-row per-head dots (requires BN == Nfull, col0 == 0)
    if constexpr (NHEAD > 0) {
        constexpr int NTL = NT / NHEAD;         // nt per head
        float sc[NT], dc[NT];
#pragma unroll
        for (int nt = 0; nt < NT; ++nt) {
            sc[nt] = att_src[nt * 16 + (lane & 15)];
            dc[nt] = att_dst[nt * 16 + (lane & 15)];
        }
#pragma unroll
        for (int j = 0; j < 4; ++j) {
            const int row = crow0 + j;
            float hs[NHEAD], hd[NHEAD];
#pragma unroll
            for (int h = 0; h < NHEAD; ++h) {
                float vs = 0.f, vd = 0.f;
#pragma unroll
                for (int t = 0; t < NTL; ++t) {
                    int nt = h * NTL + t;
                    vs += acc[nt][j] * sc[nt];
                    vd += acc[nt][j] * dc[nt];
                }
#pragma unroll
                for (int off = 1; off < 16; off <<= 1) {
                    vs += __shfl_xor(vs, off, 64);
                    vd += __shfl_xor(vd, off, 64);
                }
                hs[h] = vs; hd[h] = vd;
            }
            if ((lane & 15) == 0 && row < M) {
                if constexpr (NHEAD == 4) {
                    *(float4*)(as_out + (size_t)row * 4) = make_float4(hs[0], hs[1], hs[2], hs[3]);
                    *(float4*)(ad_out + (size_t)row * 4) = make_float4(hd[0], hd[1], hd[2], hd[3]);
                } else {
                    as_out[row] = hs[0];
                    ad_out[row] = hd[0];
                }
            }
        }
    }
}

// ---------------- CSR build ----------------
__global__ void deg_count_kernel(const int* __restrict__ dst, int* __restrict__ deg, int E) {
    int e = blockIdx.x * 256 + threadIdx.x;
    if (e < E) atomicAdd(&deg[dst[e]], 1);
}
__global__ __launch_bounds__(256) void scan1_kernel(const int* __restrict__ deg,
                                                    int* __restrict__ bsum, int N) {
    const int i = blockIdx.x * 256 + threadIdx.x;
    const int lane = threadIdx.x & 63, w = threadIdx.x >> 6;
    int v = (i < N) ? deg[i] : 0;
#pragma unroll
    for (int off = 32; off; off >>= 1) v += __shfl_xor(v, off, 64);
    __shared__ int ws[4];
    if (lane == 0) ws[w] = v;
    __syncthreads();
    if (threadIdx.x == 0) bsum[blockIdx.x] = ws[0] + ws[1] + ws[2] + ws[3];
}
__global__ __launch_bounds__(256) void scan2_kernel(const int* __restrict__ bsum,
                                                    int* __restrict__ boff, int nb) {
    const int tid = threadIdx.x, lane = tid & 63, w = tid >> 6;
    int v = (tid < nb) ? bsum[tid] : 0;
    int x = v;
#pragma unroll
    for (int off = 1; off < 64; off <<= 1) {
        int y = __shfl_up(x, off, 64);
        if (lane >= off) x += y;
    }
    __shared__ int ws[4];
    if (lane == 63) ws[w] = x;
    __syncthreads();
    int add = 0;
    for (int i = 0; i < w; ++i) add += ws[i];
    x += add;
    if (tid < nb) boff[tid] = x - v;      // exclusive
    if (tid == 255) boff[nb] = x;         // total
}
__global__ __launch_bounds__(256) void scan3_kernel(const int* __restrict__ deg,
                                                    const int* __restrict__ boff,
                                                    int* __restrict__ row_ptr, int N) {
    const int i = blockIdx.x * 256 + threadIdx.x;
    const int tid = threadIdx.x, lane = tid & 63, w = tid >> 6;
    int v = (i < N) ? deg[i] : 0;
    int x = v;
#pragma unroll
    for (int off = 1; off < 64; off <<= 1) {
        int y = __shfl_up(x, off, 64);
        if (lane >= off) x += y;
    }
    __shared__ int ws[4];
    if (lane == 63) ws[w] = x;
    __syncthreads();
    int add = 0;
    for (int k = 0; k < w; ++k) add += ws[k];
    x += add;
    int excl = x - v + boff[blockIdx.x];
    if (i < N) row_ptr[i] = excl;
    if (i == N - 1) row_ptr[N] = excl + v;
}
__global__ void selfloop_kernel(const int* __restrict__ row_ptr, int2* __restrict__ edgeA,
                                int* __restrict__ fill, int N) {
    int n = blockIdx.x * 256 + threadIdx.x;
    if (n < N) {
        int p = row_ptr[n];
        edgeA[p] = make_int2(n, n);
        fill[n] = p + 1;
    }
}
__global__ void scatter_kernel(const int* __restrict__ src, const int* __restrict__ dst,
                               int* __restrict__ fill, int2* __restrict__ edgeA, int E) {
    int e = blockIdx.x * 256 + threadIdx.x;
    if (e < E) {
        int d = dst[e];
        int pos = atomicAdd(&fill[d], 1);
        edgeA[pos] = make_int2(src[e], d);   // one 8B write (was 2 random 4B lines)
    }
}

// ---------------- edge-parallel softmax-weight precompute ----------------
template <int H>
__global__ __launch_bounds__(256) void wkernel(const int2* __restrict__ edgeA,
                                               const float* __restrict__ as,
                                               const float* __restrict__ ad,
                                               float* __restrict__ wA, int NNZ) {
    int p = blockIdx.x * 256 + threadIdx.x;
    if (p >= NNZ) return;
    const int2 e2 = edgeA[p];
    const int src = e2.x, dst = e2.y;
    if constexpr (H == 4) {
        float4 s = *(const float4*)(as + (size_t)src * 4);
        float4 d = *(const float4*)(ad + (size_t)dst * 4);
        float e;
        float4 w;
        e = s.x + d.x; e = e > 0.f ? e : 0.2f * e; w.x = __expf(e);
        e = s.y + d.y; e = e > 0.f ? e : 0.2f * e; w.y = __expf(e);
        e = s.z + d.z; e = e > 0.f ? e : 0.2f * e; w.z = __expf(e);
        e = s.w + d.w; e = e > 0.f ? e : 0.2f * e; w.w = __expf(e);
        *(float4*)(wA + (size_t)p * 4) = w;
    } else {
        float e = as[src] + ad[dst];
        e = e > 0.f ? e : 0.2f * e;
        wA[p] = __expf(e);
    }
}

// ---------------- layer-1 aggregation: 1 wave/node, 8-deep (R6 structure) --
__global__ __launch_bounds__(256) void agg1_kernel(
    const unsigned short* __restrict__ g1, const float* __restrict__ wA,
    const int* __restrict__ row_ptr, const int2* __restrict__ edgeA,
    const float* __restrict__ b1, unsigned short* __restrict__ h1b, int N) {
    int wid = (blockIdx.x * 256 + threadIdx.x) >> 6;
    int lane = threadIdx.x & 63;
    if (wid >= N) return;
    float s0 = 0.f, s1 = 0.f, s2 = 0.f, s3 = 0.f;
    float a0 = 0.f, a1 = 0.f, a2 = 0.f, a3 = 0.f;
    const int beg = row_ptr[wid], end = row_ptr[wid + 1];
    for (int idx = beg; idx < end; idx += 8) {
        int p[8];
#pragma unroll
        for (int j = 0; j < 8; ++j) { int q = idx + j; p[j] = q < end ? q : end - 1; }
        int si[8];
#pragma unroll
        for (int j = 0; j < 8; ++j) si[j] = edgeA[p[j]].x;
        float4 w[8];
#pragma unroll
        for (int j = 0; j < 8; ++j) w[j] = *(const float4*)(wA + (size_t)p[j] * 4);
        ushort4 g[8];
#pragma unroll
        for (int j = 0; j < 8; ++j)
            g[j] = *(const ushort4*)(g1 + ((size_t)si[j] << 8) + lane * 4);
#pragma unroll
        for (int j = 0; j < 8; ++j) {
            const float m = (idx + j < end) ? 1.f : 0.f;
            const float wx = w[j].x * m, wy = w[j].y * m;
            const float wz = w[j].z * m, ww = w[j].w * m;
            s0 += wx; a0 += wx * us2f(g[j].x);
            s1 += wy; a1 += wy * us2f(g[j].y);
            s2 += wz; a2 += wz * us2f(g[j].z);
            s3 += ww; a3 += ww * us2f(g[j].w);
        }
    }
    size_t base = (size_t)wid * 256;
    float o;
    o = a0 / s0 + b1[lane];       o = o > 0.f ? o : expm1f(o); h1b[base + lane]       = f2us(o);
    o = a1 / s1 + b1[64 + lane];  o = o > 0.f ? o : expm1f(o); h1b[base + 64 + lane]  = f2us(o);
    o = a2 / s2 + b1[128 + lane]; o = o > 0.f ? o : expm1f(o); h1b[base + 128 + lane] = f2us(o);
    o = a3 / s3 + b1[192 + lane]; o = o > 0.f ? o : expm1f(o); h1b[base + 192 + lane] = f2us(o);
}

// ---------------- layer-2 aggregation + classifier: 1 wave/node, 16-deep ---
__global__ __launch_bounds__(256) void agg2_kernel(
    const unsigned short* __restrict__ g2, const float* __restrict__ wA,
    const int* __restrict__ row_ptr, const int2* __restrict__ edgeA,
    const float* __restrict__ b2, const float* __restrict__ Wc,
    const float* __restrict__ bc, float* __restrict__ out, int N) {
    int wid = (blockIdx.x * 256 + threadIdx.x) >> 6;
    int lane = threadIdx.x & 63;
    if (wid >= N) return;
    float s = 0.f, a = 0.f;
    const int beg = row_ptr[wid], end = row_ptr[wid + 1];
    for (int idx = beg; idx < end; idx += 16) {
        int p[16];
#pragma unroll
        for (int j = 0; j < 16; ++j) { int q = idx + j; p[j] = q < end ? q : end - 1; }
        int si[16];
#pragma unroll
        for (int j = 0; j < 16; ++j) si[j] = edgeA[p[j]].x;
        float w[16];
#pragma unroll
        for (int j = 0; j < 16; ++j) w[j] = wA[p[j]];
        unsigned short g[16];
#pragma unroll
        for (int j = 0; j < 16; ++j) g[j] = g2[((size_t)si[j] << 6) + lane];
#pragma unroll
        for (int j = 0; j < 16; ++j) {
            const float m = (idx + j < end) ? 1.f : 0.f;
            const float wj = w[j] * m;
            s += wj; a += wj * us2f(g[j]);
        }
    }
    float h = a / s + b2[lane];
    h = h > 0.f ? h : expm1f(h);
    float c0 = h * Wc[lane * 2 + 0];
    float c1 = h * Wc[lane * 2 + 1];
#pragma unroll
    for (int off = 32; off; off >>= 1) {
        c0 += __shfl_xor(c0, off, 64);
        c1 += __shfl_xor(c1, off, 64);
    }
    if (lane == 0) {
        out[(size_t)wid * 2 + 0] = c0 + bc[0];
        out[(size_t)wid * 2 + 1] = c1 + bc[1];
    }
}

extern "C" void kernel_launch(void* const* d_in, const int* in_sizes, int n_in,
                              void* d_out, int out_size, void* d_ws, size_t ws_size,
                              hipStream_t stream) {
    const float* x        = (const float*)d_in[0];
    const int*   ei       = (const int*)d_in[1];
    const float* W1       = (const float*)d_in[2];
    const float* att1_src = (const float*)d_in[3];
    const float* att1_dst = (const float*)d_in[4];
    const float* b1       = (const float*)d_in[5];
    const float* W2       = (const float*)d_in[6];
    const float* att2_src = (const float*)d_in[7];
    const float* att2_dst = (const float*)d_in[8];
    const float* b2       = (const float*)d_in[9];
    const float* Wc       = (const float*)d_in[10];
    const float* bc       = (const float*)d_in[11];
    float* out = (float*)d_out;

    const int N = in_sizes[0] / IN_DIM;
    const int E = in_sizes[1] / 2;
    const int NNZ = E + N;
    const int* srcI = ei;
    const int* dstI = ei + E;

    // workspace layout (~85 MB): bf16 bufs | fp32 | edgeA(int2) | ints
    unsigned short* g1b = (unsigned short*)d_ws;      // N*256 (head-interleaved)
    unsigned short* h1b = g1b + (size_t)N * 256;      // N*256
    unsigned short* g2b = h1b + (size_t)N * 256;      // N*64
    unsigned short* W1T = g2b + (size_t)N * 64;       // 256*128
    unsigned short* W2T = W1T + 256 * 128;            // 64*256
    float* as1 = (float*)(W2T + 64 * 256);            // N*4
    float* ad1 = as1 + (size_t)N * 4;                 // N*4
    float* as2 = ad1 + (size_t)N * 4;                 // N
    float* ad2 = as2 + N;                             // N
    float* wA1 = ad2 + N;                             // NNZ*4 (16B-aligned)
    float* wA2 = wA1 + (size_t)NNZ * 4;               // NNZ
    int2* edgeA  = (int2*)(wA2 + NNZ);                // NNZ (8B-aligned)
    int* deg     = (int*)(edgeA + NNZ);               // N
    int* row_ptr = deg + N;                           // N+1
    int* fill    = row_ptr + N + 1;                   // N
    int* bsum    = fill + N;                          // 256
    int* boff    = bsum + 256;                        // 257

    const int nB = (N + 255) / 256;
    const int eB = (E + 255) / 256;
    const int pB = (NNZ + 255) / 256;
    const int wB = ((N * 64) + 255) / 256;            // one wave per node
    const int nb = nB;                                // scan partials (<=256)

    // setup (deg init + weight transposes)
    setup_kernel<<<nB, 256, 0, stream>>>(W1, W2, W1T, W2T, deg, N);

    // CSR build
    deg_count_kernel<<<eB, 256, 0, stream>>>(dstI, deg, E);
    scan1_kernel<<<nB, 256, 0, stream>>>(deg, bsum, N);
    scan2_kernel<<<1, 256, 0, stream>>>(bsum, boff, nb);
    scan3_kernel<<<nB, 256, 0, stream>>>(deg, boff, row_ptr, N);
    selfloop_kernel<<<nB, 256, 0, stream>>>(row_ptr, edgeA, fill, N);
    scatter_kernel<<<eB, 256, 0, stream>>>(srcI, dstI, fill, edgeA, E);

    // layer 1: g1 = x @ W1 (fp32 A staged to bf16), head-interleaved out,
    // alpha1 fused into epilogue (BN=256 = full width)
    gemm_mfma_kernel<256, 64, 128, true, true, 4>
        <<<dim3(1, (N + 63) / 64), 256, 0, stream>>>(x, W1T, g1b,
                                                     att1_src, att1_dst, as1, ad1, N, 256);
    wkernel<4><<<pB, 256, 0, stream>>>(edgeA, as1, ad1, wA1, NNZ);
    agg1_kernel<<<wB, 256, 0, stream>>>(g1b, wA1, row_ptr, edgeA, b1, h1b, N);

    // layer 2: g2 = h1 @ W2, alpha2 fused into epilogue (BN=64 = full width)
    gemm_mfma_kernel<64, 128, 256, false, false, 1>
        <<<dim3(1, (N + 63) / 64), 256, 0, stream>>>(h1b, W2T, g2b,
                                                     att2_src, att2_dst, as2, ad2, N, 64);
    wkernel<1><<<pB, 256, 0, stream>>>(edgeA, as2, ad2, wA2, NNZ);
    agg2_kernel<<<wB, 256, 0, stream>>>(g2b, wA2, row_ptr, edgeA, b2, Wc, bc, out, N);
}